// Round 1
// baseline (249.594 us; speedup 1.0000x reference)
//
#include <hip/hip_runtime.h>
#include <math.h>

#define B 1024
#define D 128
#define TDIM 1

constexpr float THR   = 0.05f;
constexpr float LAM1f = 1.0f;
constexpr float LAM2f = 0.5f;
constexpr float EPSf  = 1e-8f;

struct SelState {
  unsigned n_pos;
  unsigned prefix;
  unsigned k;
  float    T_eff;
};

// ---- column mean/std (ddof=1), two-pass for accuracy ----
__global__ void __launch_bounds__(256) col_stats(const float* __restrict__ x,
                                                 float* __restrict__ m,
                                                 float* __restrict__ s) {
  int d = blockIdx.x;           // 0..127
  int t = threadIdx.x;          // 0..255
  float v[4];
#pragma unroll
  for (int k = 0; k < 4; ++k) v[k] = x[(t + k * 256) * D + d];
  __shared__ float red[256];
  red[t] = v[0] + v[1] + v[2] + v[3];
  __syncthreads();
  for (int o = 128; o > 0; o >>= 1) {
    if (t < o) red[t] += red[t + o];
    __syncthreads();
  }
  __shared__ float mean_sh;
  if (t == 0) mean_sh = red[0] * (1.0f / 1024.0f);
  __syncthreads();
  float mean = mean_sh;
  float sq = 0.f;
#pragma unroll
  for (int k = 0; k < 4; ++k) { float dv = v[k] - mean; sq += dv * dv; }
  __syncthreads();
  red[t] = sq;
  __syncthreads();
  for (int o = 128; o > 0; o >>= 1) {
    if (t < o) red[t] += red[t + o];
    __syncthreads();
  }
  if (t == 0) {
    float var = red[0] * (1.0f / 1023.0f);
    float sd = sqrtf(var);
    if (sd < 1e-6f) sd = 1e-6f;
    m[d] = mean;
    s[d] = sd;
  }
}

// ---- normalize rows; emit xn, z2 (col TDIM), r2o (sum of xn^2 over d!=TDIM) ----
__global__ void __launch_bounds__(128) normalize_rows(const float* __restrict__ x,
                                                      const float* __restrict__ m,
                                                      const float* __restrict__ s,
                                                      float* __restrict__ xn,
                                                      float* __restrict__ z2,
                                                      float* __restrict__ r2o) {
  int i = blockIdx.x;           // row
  int d = threadIdx.x;          // 0..127
  float v = (x[i * D + d] - m[d]) / s[d];
  xn[i * D + d] = v;
  if (d == TDIM) z2[i] = v;
  float c = (d == TDIM) ? 0.f : v * v;
  __shared__ float red[128];
  red[d] = c;
  __syncthreads();
  for (int o = 64; o > 0; o >>= 1) {
    if (d < o) red[d] += red[d + o];
    __syncthreads();
  }
  if (d == 0) r2o[i] = red[0];
}

// ---- radix-select histogram pass over masked d2 values ----
__global__ void __launch_bounds__(256) hist_pass(const float* __restrict__ y,
                                                 const float* __restrict__ z2,
                                                 unsigned* __restrict__ hist,
                                                 const SelState* __restrict__ st,
                                                 int level) {
  __shared__ unsigned lh[2048];
  for (int b = threadIdx.x; b < 2048; b += 256) lh[b] = 0;
  __syncthreads();
  int i = blockIdx.x;
  float yi = y[i], zi = z2[i];
  unsigned pref = st->prefix;
  for (int j = threadIdx.x; j < B; j += 256) {
    if (j == i) continue;
    if (fabsf(yi - y[j]) > THR) continue;
    float dz = zi - z2[j];
    unsigned bits = __float_as_uint(dz * dz);
    if (level == 0) {
      atomicAdd(&lh[bits >> 21], 1u);
    } else if (level == 1) {
      if ((bits >> 21) == pref) atomicAdd(&lh[(bits >> 10) & 0x7FFu], 1u);
    } else {
      if ((bits >> 10) == pref) atomicAdd(&lh[bits & 0x3FFu], 1u);
    }
  }
  __syncthreads();
  for (int b = threadIdx.x; b < 2048; b += 256) {
    unsigned c = lh[b];
    if (c) atomicAdd(&hist[b], c);
  }
}

// ---- scan histogram, descend one radix level; zero hist for next pass ----
__global__ void __launch_bounds__(256) scan_pass(unsigned* __restrict__ hist,
                                                 SelState* __restrict__ st,
                                                 int level) {
  __shared__ unsigned lh[2048];
  int nb = (level == 2) ? 1024 : 2048;
  for (int b = threadIdx.x; b < nb; b += 256) lh[b] = hist[b];
  __syncthreads();
  if (threadIdx.x == 0) {
    if (level == 0) {
      unsigned long long total = 0;
      for (int b = 0; b < nb; ++b) total += lh[b];
      st->n_pos = (unsigned)total;
      if (total == 0) {
        st->prefix = 0; st->k = 0; st->T_eff = 2.0f;
      } else {
        unsigned k = (unsigned)((total - 1) >> 1);
        unsigned cum = 0; int b = 0;
        for (; b < nb; ++b) { if (cum + lh[b] > k) break; cum += lh[b]; }
        st->prefix = (unsigned)b;
        st->k = k - cum;
      }
    } else if (level == 1) {
      if (st->n_pos) {
        unsigned k = st->k, cum = 0; int b = 0;
        for (; b < nb; ++b) { if (cum + lh[b] > k) break; cum += lh[b]; }
        st->prefix = (st->prefix << 11) | (unsigned)b;
        st->k = k - cum;
      }
    } else {
      if (st->n_pos) {
        unsigned k = st->k, cum = 0; int b = 0;
        for (; b < nb; ++b) { if (cum + lh[b] > k) break; cum += lh[b]; }
        unsigned bits = (st->prefix << 10) | (unsigned)b;
        float med = __uint_as_float(bits);
        st->T_eff = fmaxf(med, 1e-6f);
      }
    }
  }
  __syncthreads();
  for (int b = threadIdx.x; b < 2048; b += 256) hist[b] = 0;
}

// ---- main pairwise pass: per-row num/den1/den2 and loss contribution ----
__global__ void __launch_bounds__(256) pair_main(const float* __restrict__ y,
                                                 const float* __restrict__ z2,
                                                 const float* __restrict__ r2o,
                                                 const float* __restrict__ xn,
                                                 const SelState* __restrict__ st,
                                                 float* __restrict__ loss_i,
                                                 unsigned* __restrict__ haspos_i) {
  int i = blockIdx.x;
  __shared__ float xi[D];
  for (int d = threadIdx.x; d < D; d += 256) xi[d] = xn[i * D + d];
  __syncthreads();
  float yi = y[i], zi = z2[i], ri = r2o[i];
  float invT = 1.0f / st->T_eff;
  float num = 0.f, den1 = 0.f, den2 = 0.f;
  int cnt = 0;
  for (int j = threadIdx.x; j < B; j += 256) {
    if (j == i) continue;
    float zj = z2[j];
    float dz = zi - zj;
    float d2 = dz * dz;
    float K2 = expf(-d2 * invT);
    den1 += K2;
    if (fabsf(yi - y[j]) <= THR) {
      num += K2;
      cnt++;
      const float* xj = xn + j * D;
      float dot = 0.f;
#pragma unroll
      for (int d = 0; d < D; d += 4) {
        float4 a = *(const float4*)(xi + d);
        float4 bb = *(const float4*)(xj + d);
        dot += a.x * bb.x + a.y * bb.y + a.z * bb.z + a.w * bb.w;
      }
      float dot_o = dot - zi * zj;
      float sq = (ri + r2o[j] - 2.f * dot_o) * (1.0f / 127.0f);
      sq = fmaxf(sq, 0.f);
      den2 += expf(-sq * invT);
    }
  }
  __shared__ float rn[256], r1[256], r2s[256];
  __shared__ int rc[256];
  int t = threadIdx.x;
  rn[t] = num; r1[t] = den1; r2s[t] = den2; rc[t] = cnt;
  __syncthreads();
  for (int o = 128; o > 0; o >>= 1) {
    if (t < o) {
      rn[t] += rn[t + o];
      r1[t] += r1[t + o];
      r2s[t] += r2s[t + o];
      rc[t] += rc[t + o];
    }
    __syncthreads();
  }
  if (t == 0) {
    float denom = LAM1f * r1[0] + LAM2f * r2s[0] + EPSf;
    float frac = rn[0] / denom;
    frac = fminf(fmaxf(frac, 1e-12f), 1.0f - 1e-7f);
    int hp = rc[0] > 0 ? 1 : 0;
    loss_i[i] = hp ? -logf(frac) : 0.f;
    haspos_i[i] = (unsigned)hp;
  }
}

// ---- final deterministic reduction to scalar loss ----
__global__ void __launch_bounds__(256) finalize(const float* __restrict__ loss_i,
                                                const unsigned* __restrict__ haspos_i,
                                                float* __restrict__ out) {
  __shared__ float rs[256];
  __shared__ unsigned rcnt[256];
  int t = threadIdx.x;
  float sv = 0.f;
  unsigned c = 0;
  for (int i = t; i < B; i += 256) { sv += loss_i[i]; c += haspos_i[i]; }
  rs[t] = sv; rcnt[t] = c;
  __syncthreads();
  for (int o = 128; o > 0; o >>= 1) {
    if (t < o) { rs[t] += rs[t + o]; rcnt[t] += rcnt[t + o]; }
    __syncthreads();
  }
  if (t == 0) out[0] = (rcnt[0] > 0) ? rs[0] / (float)rcnt[0] : 0.f;
}

extern "C" void kernel_launch(void* const* d_in, const int* in_sizes, int n_in,
                              void* d_out, int out_size, void* d_ws, size_t ws_size,
                              hipStream_t stream) {
  const float* x = (const float*)d_in[0];   // (1024,128) f32
  const float* y = (const float*)d_in[1];   // (1024,)    f32
  float* out = (float*)d_out;               // scalar f32

  char* w = (char*)d_ws;
  float* m    = (float*)w;            w += 128 * sizeof(float);
  float* s    = (float*)w;            w += 128 * sizeof(float);
  float* xn   = (float*)w;            w += (size_t)B * D * sizeof(float);
  float* z2   = (float*)w;            w += B * sizeof(float);
  float* r2o  = (float*)w;            w += B * sizeof(float);
  unsigned* hist = (unsigned*)w;      w += 2048 * sizeof(unsigned);
  SelState* st = (SelState*)w;        w += 64;
  float* loss_i = (float*)w;          w += B * sizeof(float);
  unsigned* haspos_i = (unsigned*)w;  w += B * sizeof(unsigned);

  // zero histogram + selection state each call (ws is poisoned, not re-poisoned)
  hipMemsetAsync(hist, 0, 2048 * sizeof(unsigned) + 64, stream);

  col_stats<<<D, 256, 0, stream>>>(x, m, s);
  normalize_rows<<<B, 128, 0, stream>>>(x, m, s, xn, z2, r2o);

  hist_pass<<<B, 256, 0, stream>>>(y, z2, hist, st, 0);
  scan_pass<<<1, 256, 0, stream>>>(hist, st, 0);
  hist_pass<<<B, 256, 0, stream>>>(y, z2, hist, st, 1);
  scan_pass<<<1, 256, 0, stream>>>(hist, st, 1);
  hist_pass<<<B, 256, 0, stream>>>(y, z2, hist, st, 2);
  scan_pass<<<1, 256, 0, stream>>>(hist, st, 2);

  pair_main<<<B, 256, 0, stream>>>(y, z2, r2o, xn, st, loss_i, haspos_i);
  finalize<<<1, 256, 0, stream>>>(loss_i, haspos_i, out);
}

// Round 2
// 81.097 us; speedup vs baseline: 3.0777x; 3.0777x over previous
//
#include <hip/hip_runtime.h>
#include <math.h>

#define B 1024
#define D 128
#define TDIM 1

constexpr float THR   = 0.05f;
constexpr float LAM1f = 1.0f;
constexpr float LAM2f = 0.5f;
constexpr float EPSf  = 1e-8f;

struct SelState {
  unsigned n_pos;
  unsigned prefix;
  unsigned k;
  float    T_eff;
};

// ---- column mean/std (ddof=1), two-pass for accuracy ----
__global__ void __launch_bounds__(256) col_stats(const float* __restrict__ x,
                                                 float* __restrict__ m,
                                                 float* __restrict__ s) {
  int d = blockIdx.x;           // 0..127
  int t = threadIdx.x;          // 0..255
  float v[4];
#pragma unroll
  for (int k = 0; k < 4; ++k) v[k] = x[(t + k * 256) * D + d];
  __shared__ float red[256];
  red[t] = v[0] + v[1] + v[2] + v[3];
  __syncthreads();
  for (int o = 128; o > 0; o >>= 1) {
    if (t < o) red[t] += red[t + o];
    __syncthreads();
  }
  __shared__ float mean_sh;
  if (t == 0) mean_sh = red[0] * (1.0f / 1024.0f);
  __syncthreads();
  float mean = mean_sh;
  float sq = 0.f;
#pragma unroll
  for (int k = 0; k < 4; ++k) { float dv = v[k] - mean; sq += dv * dv; }
  __syncthreads();
  red[t] = sq;
  __syncthreads();
  for (int o = 128; o > 0; o >>= 1) {
    if (t < o) red[t] += red[t + o];
    __syncthreads();
  }
  if (t == 0) {
    float var = red[0] * (1.0f / 1023.0f);
    float sd = sqrtf(var);
    if (sd < 1e-6f) sd = 1e-6f;
    m[d] = mean;
    s[d] = sd;
  }
}

// ---- normalize rows; emit xn, z2 (col TDIM), r2o (sum of xn^2 over d!=TDIM) ----
__global__ void __launch_bounds__(128) normalize_rows(const float* __restrict__ x,
                                                      const float* __restrict__ m,
                                                      const float* __restrict__ s,
                                                      float* __restrict__ xn,
                                                      float* __restrict__ z2,
                                                      float* __restrict__ r2o) {
  int i = blockIdx.x;           // row
  int d = threadIdx.x;          // 0..127
  float v = (x[i * D + d] - m[d]) / s[d];
  xn[i * D + d] = v;
  if (d == TDIM) z2[i] = v;
  float c = (d == TDIM) ? 0.f : v * v;
  __shared__ float red[128];
  red[d] = c;
  __syncthreads();
  for (int o = 64; o > 0; o >>= 1) {
    if (d < o) red[d] += red[d + o];
    __syncthreads();
  }
  if (d == 0) r2o[i] = red[0];
}

// ---- radix-select histogram pass over masked d2 values ----
__global__ void __launch_bounds__(256) hist_pass(const float* __restrict__ y,
                                                 const float* __restrict__ z2,
                                                 unsigned* __restrict__ hist,
                                                 const SelState* __restrict__ st,
                                                 int level) {
  __shared__ unsigned lh[2048];
  for (int b = threadIdx.x; b < 2048; b += 256) lh[b] = 0;
  __syncthreads();
  int i = blockIdx.x;
  float yi = y[i], zi = z2[i];
  unsigned pref = st->prefix;
  for (int j = threadIdx.x; j < B; j += 256) {
    if (j == i) continue;
    if (fabsf(yi - y[j]) > THR) continue;
    float dz = zi - z2[j];
    unsigned bits = __float_as_uint(dz * dz);
    if (level == 0) {
      atomicAdd(&lh[bits >> 21], 1u);
    } else if (level == 1) {
      if ((bits >> 21) == pref) atomicAdd(&lh[(bits >> 10) & 0x7FFu], 1u);
    } else {
      if ((bits >> 10) == pref) atomicAdd(&lh[bits & 0x3FFu], 1u);
    }
  }
  __syncthreads();
  for (int b = threadIdx.x; b < 2048; b += 256) {
    unsigned c = lh[b];
    if (c) atomicAdd(&hist[b], c);
  }
}

// ---- parallel scan of histogram: descend one radix level; zero hist after ----
__global__ void __launch_bounds__(256) scan_pass(unsigned* __restrict__ hist,
                                                 SelState* __restrict__ st,
                                                 int level) {
  const int nb  = (level == 2) ? 1024 : 2048;
  const int per = nb >> 8;                     // 8 or 4 buckets/thread
  int t = threadIdx.x;
  unsigned local[8];
  unsigned lsum = 0;
#pragma unroll
  for (int q = 0; q < 8; ++q) {
    unsigned v = (q < per) ? hist[t * per + q] : 0u;
    local[q] = v;
    lsum += v;
  }
  // wave-level inclusive scan of per-thread sums (wave64)
  unsigned incl = lsum;
#pragma unroll
  for (int o = 1; o < 64; o <<= 1) {
    unsigned nbr = __shfl_up(incl, o, 64);
    if ((t & 63) >= o) incl += nbr;
  }
  __shared__ unsigned wsum[4];
  __shared__ unsigned tot_sh;
  if ((t & 63) == 63) wsum[t >> 6] = incl;
  __syncthreads();
  unsigned wpre = 0;
  for (int wv = 0; wv < (t >> 6); ++wv) wpre += wsum[wv];
  incl += wpre;
  unsigned excl = incl - lsum;
  if (t == 255) tot_sh = incl;
  __syncthreads();
  unsigned total = tot_sh;

  bool active = true;
  unsigned kk = 0;
  if (level == 0) {
    if (t == 0) {
      st->n_pos = total;
      if (total == 0) { st->prefix = 0; st->k = 0; st->T_eff = 2.0f; }
    }
    if (total == 0) active = false;
    else kk = (total - 1) >> 1;
  } else {
    if (st->n_pos == 0) active = false;
    else kk = st->k;
  }

  if (active && kk >= excl && kk < incl) {   // exactly one thread
    unsigned cum = excl;
    for (int q = 0; q < per; ++q) {
      if (cum + local[q] > kk) {
        unsigned b = (unsigned)(t * per + q);
        if (level == 0)      { st->prefix = b; st->k = kk - cum; }
        else if (level == 1) { st->prefix = (st->prefix << 11) | b; st->k = kk - cum; }
        else {
          unsigned bits = (st->prefix << 10) | b;
          st->T_eff = fmaxf(__uint_as_float(bits), 1e-6f);
        }
        break;
      }
      cum += local[q];
    }
  }
  __syncthreads();
  for (int b2 = t; b2 < 2048; b2 += 256) hist[b2] = 0;
}

// ---- main pairwise pass: per-row num/den1/den2 and loss contribution ----
__global__ void __launch_bounds__(256) pair_main(const float* __restrict__ y,
                                                 const float* __restrict__ z2,
                                                 const float* __restrict__ r2o,
                                                 const float* __restrict__ xn,
                                                 const SelState* __restrict__ st,
                                                 float* __restrict__ loss_i,
                                                 unsigned* __restrict__ haspos_i) {
  int i = blockIdx.x;
  __shared__ float xi[D];
  for (int d = threadIdx.x; d < D; d += 256) xi[d] = xn[i * D + d];
  __syncthreads();
  float yi = y[i], zi = z2[i], ri = r2o[i];
  float invT = 1.0f / st->T_eff;
  float num = 0.f, den1 = 0.f, den2 = 0.f;
  int cnt = 0;
  for (int j = threadIdx.x; j < B; j += 256) {
    if (j == i) continue;
    float zj = z2[j];
    float dz = zi - zj;
    float d2 = dz * dz;
    float K2 = expf(-d2 * invT);
    den1 += K2;
    if (fabsf(yi - y[j]) <= THR) {
      num += K2;
      cnt++;
      const float* xj = xn + j * D;
      float dot = 0.f;
#pragma unroll
      for (int d = 0; d < D; d += 4) {
        float4 a = *(const float4*)(xi + d);
        float4 bb = *(const float4*)(xj + d);
        dot += a.x * bb.x + a.y * bb.y + a.z * bb.z + a.w * bb.w;
      }
      float dot_o = dot - zi * zj;
      float sq = (ri + r2o[j] - 2.f * dot_o) * (1.0f / 127.0f);
      sq = fmaxf(sq, 0.f);
      den2 += expf(-sq * invT);
    }
  }
  __shared__ float rn[256], r1[256], r2s[256];
  __shared__ int rc[256];
  int t = threadIdx.x;
  rn[t] = num; r1[t] = den1; r2s[t] = den2; rc[t] = cnt;
  __syncthreads();
  for (int o = 128; o > 0; o >>= 1) {
    if (t < o) {
      rn[t] += rn[t + o];
      r1[t] += r1[t + o];
      r2s[t] += r2s[t + o];
      rc[t] += rc[t + o];
    }
    __syncthreads();
  }
  if (t == 0) {
    float denom = LAM1f * r1[0] + LAM2f * r2s[0] + EPSf;
    float frac = rn[0] / denom;
    frac = fminf(fmaxf(frac, 1e-12f), 1.0f - 1e-7f);
    int hp = rc[0] > 0 ? 1 : 0;
    loss_i[i] = hp ? -logf(frac) : 0.f;
    haspos_i[i] = (unsigned)hp;
  }
}

// ---- final deterministic reduction to scalar loss ----
__global__ void __launch_bounds__(256) finalize(const float* __restrict__ loss_i,
                                                const unsigned* __restrict__ haspos_i,
                                                float* __restrict__ out) {
  __shared__ float rs[256];
  __shared__ unsigned rcnt[256];
  int t = threadIdx.x;
  float sv = 0.f;
  unsigned c = 0;
  for (int i = t; i < B; i += 256) { sv += loss_i[i]; c += haspos_i[i]; }
  rs[t] = sv; rcnt[t] = c;
  __syncthreads();
  for (int o = 128; o > 0; o >>= 1) {
    if (t < o) { rs[t] += rs[t + o]; rcnt[t] += rcnt[t + o]; }
    __syncthreads();
  }
  if (t == 0) out[0] = (rcnt[0] > 0) ? rs[0] / (float)rcnt[0] : 0.f;
}

extern "C" void kernel_launch(void* const* d_in, const int* in_sizes, int n_in,
                              void* d_out, int out_size, void* d_ws, size_t ws_size,
                              hipStream_t stream) {
  const float* x = (const float*)d_in[0];   // (1024,128) f32
  const float* y = (const float*)d_in[1];   // (1024,)    f32
  float* out = (float*)d_out;               // scalar f32

  char* w = (char*)d_ws;
  float* m    = (float*)w;            w += 128 * sizeof(float);
  float* s    = (float*)w;            w += 128 * sizeof(float);
  float* xn   = (float*)w;            w += (size_t)B * D * sizeof(float);
  float* z2   = (float*)w;            w += B * sizeof(float);
  float* r2o  = (float*)w;            w += B * sizeof(float);
  unsigned* hist = (unsigned*)w;      w += 2048 * sizeof(unsigned);
  SelState* st = (SelState*)w;        w += 64;
  float* loss_i = (float*)w;          w += B * sizeof(float);
  unsigned* haspos_i = (unsigned*)w;  w += B * sizeof(unsigned);

  // zero histogram + selection state each call (ws is poisoned, not re-poisoned)
  hipMemsetAsync(hist, 0, 2048 * sizeof(unsigned) + 64, stream);

  col_stats<<<D, 256, 0, stream>>>(x, m, s);
  normalize_rows<<<B, 128, 0, stream>>>(x, m, s, xn, z2, r2o);

  hist_pass<<<B, 256, 0, stream>>>(y, z2, hist, st, 0);
  scan_pass<<<1, 256, 0, stream>>>(hist, st, 0);
  hist_pass<<<B, 256, 0, stream>>>(y, z2, hist, st, 1);
  scan_pass<<<1, 256, 0, stream>>>(hist, st, 1);
  hist_pass<<<B, 256, 0, stream>>>(y, z2, hist, st, 2);
  scan_pass<<<1, 256, 0, stream>>>(hist, st, 2);

  pair_main<<<B, 256, 0, stream>>>(y, z2, r2o, xn, st, loss_i, haspos_i);
  finalize<<<1, 256, 0, stream>>>(loss_i, haspos_i, out);
}